// Round 1
// baseline (161.787 us; speedup 1.0000x reference)
//
#include <hip/hip_runtime.h>

// GlobalGraphConv: B=4, C=64, N=4096, IC=32
// f[i,j] = a_i + p_j (outer sum); lrelu piecewise-linear =>
// exp(lrelu(a_i+p_j)) factorizes per branch; sort p, softmax row = threshold
// lookup into prefix/suffix sums of weighted g_x rows. O(N^2 C) -> O(N C).
// R9: 5 -> 4 dispatches. K3 eliminated: K34 blocks redundantly recompute the
// full-batch e-arrays + all-chunk weighted sums in LDS (L2-resident, ~1 MB
// gathers/block), then emit PreS/SufS (shfl scans) + PreG/SufG for their own
// 2 chunks. Modeled busy time ~30us; the rest is dispatch overhead, so the
// dispatch count is the lever.

#define B  4
#define C  64
#define N  4096
#define IC 32
#define NS 4104   // per-batch stride for PreS/SufS (>= N+1)
#define NR 4097   // rows per batch for PreG/SufG (k = 0..N)
#define MAGIC 0x13572468

// workspace offsets (in floats)
#define OFF_FLAG   248          // int: C_k nonzero marker (MAGIC if nonzero)
#define OFF_A      256
#define OFF_P      (OFF_A + B*N)
#define OFF_Q      (OFF_P + B*N)
#define OFF_PERM   (OFF_Q + B*N)            // ints
#define OFF_PRES   (OFF_PERM + B*N)
#define OFF_SUFS   (OFF_PRES + B*NS)
#define OFF_S1     (OFF_SUFS + B*NS)        // (unused since R9; keeps offset chain)
#define OFF_S2     (OFF_S1 + B*64*64)
#define OFF_GX     (OFF_S2 + B*64*64)       // B*N*64, layout [b][n][o]
#define OFF_PREG   (OFF_GX + B*N*64)        // B*NR*64, layout [b][k][o]
#define OFF_SUFG   (OFF_PREG + B*NR*64)

//========== K1: gx = g_w@x + g_b; a,p; + grid-strided C_k zero scan ==========
__global__ __launch_bounds__(256) void k1_gx(
    const float* __restrict__ x, const float* __restrict__ g_w,
    const float* __restrict__ g_b, const float* __restrict__ theta_w,
    const float* __restrict__ theta_b, const float* __restrict__ phi_w,
    const float* __restrict__ phi_b, const float* __restrict__ cp_w,
    const float* __restrict__ Ck, float* __restrict__ ws) {
  __shared__ float gwT[C * C];   // [cc][o]
  __shared__ float xl[C * 16];   // [cc][nn]
  __shared__ float lu[C], lv[C], cst[2];
  const int tid = threadIdx.x;
  const int b = blockIdx.x >> 8;           // 256 blocks per batch
  const int n0 = (blockIdx.x & 255) << 4;  // 16 nodes per block
  for (int idx = tid; idx < C * C; idx += 256) {
    int o = idx >> 6, cc = idx & 63;
    gwT[cc * C + o] = g_w[idx];
  }
  for (int idx = tid; idx < C * 16; idx += 256) {
    int cc = idx >> 4, nn = idx & 15;
    xl[idx] = x[(size_t)((b << 6) + cc) * N + n0 + nn];
  }
  if (tid < 64) {
    float u = 0.f;
    for (int k = 0; k < IC; ++k) u += cp_w[k] * theta_w[k * C + tid];
    lu[tid] = u;
  } else if (tid < 128) {
    int c = tid - 64;
    float v = 0.f;
    for (int k = 0; k < IC; ++k) v += cp_w[IC + k] * phi_w[k * C + c];
    lv[c] = v;
  } else if (tid == 128) {
    float ca = 0.f, cp2 = 0.f;
    for (int k = 0; k < IC; ++k) { ca += cp_w[k] * theta_b[k]; cp2 += cp_w[IC + k] * phi_b[k]; }
    cst[0] = ca; cst[1] = cp2;
  }
  __syncthreads();
  if (tid < 16) {   // a,p: one thread per node
    float au = cst[0], pu = cst[1];
    for (int cc = 0; cc < C; ++cc) {
      float xv = xl[cc * 16 + tid];
      au += lu[cc] * xv;
      pu += lv[cc] * xv;
    }
    ws[OFF_A + (b << 12) + n0 + tid] = au;
    ws[OFF_P + (b << 12) + n0 + tid] = pu;
  }
  const int o = tid & 63, g4 = tid >> 6;
  float bb = g_b[o];
  float acc0 = bb, acc1 = bb, acc2 = bb, acc3 = bb;
  for (int cc = 0; cc < C; ++cc) {
    float gv = gwT[cc * C + o];                 // stride-1: conflict-free
    const float* xr = &xl[cc * 16 + (g4 << 2)]; // wave broadcast
    acc0 += gv * xr[0]; acc1 += gv * xr[1]; acc2 += gv * xr[2]; acc3 += gv * xr[3];
  }
  float* gx = ws + OFF_GX + (size_t)((b << 12) + n0 + (g4 << 2)) * C + o;
  gx[0] = acc0; gx[64] = acc1; gx[128] = acc2; gx[192] = acc3;
  // ---- C_k zero scan (67 MB, grid-strided, HBM-bound) ----
  const float4* c4 = (const float4*)Ck;
  bool nz = false;
  int idx = (blockIdx.x << 8) + tid;           // 262144 threads, 16 f4 each
  for (int t = 0; t < 16; ++t) {
    float4 v = c4[idx];
    nz |= (v.x != 0.f) | (v.y != 0.f) | (v.z != 0.f) | (v.w != 0.f);
    idx += 262144;
  }
  if (__any(nz) && (tid & 63) == 0)
    atomicExch((int*)ws + OFF_FLAG, MAGIC);
}

//========== K2: rank-by-counting + scatter (fused) ===========================
// grid 512: b = bid>>7, 128 blocks/batch, 32 rows each; 1024 thr = 32r x 32c
__global__ __launch_bounds__(1024) void k2_rank(float* __restrict__ ws) {
  __shared__ float lp[N];            // 16 KB: full batch p
  __shared__ int partials[32][33];   // +1 pad
  const int tid = threadIdx.x;
  const int b = blockIdx.x >> 7;
  const int rg = blockIdx.x & 127;
  const float* p = ws + OFF_P + b * N;
  ((float4*)lp)[tid] = ((const float4*)p)[tid];
  const int row = tid & 31, chunk = tid >> 5;
  const int i = (rg << 5) + row;     // batch-local row index
  __syncthreads();
  const float my = lp[i];
  const int c0 = chunk << 7;         // 128 cols per chunk
  const float4* lp4 = (const float4*)(lp + c0);
  int r0 = 0, r1 = 0, r2 = 0, r3 = 0;
  for (int j = 0; j < 32; ++j) {
    float4 v = lp4[j];               // 2 addrs/wave: free 2-way broadcast
    int k = c0 + (j << 2);
    r0 += (v.x < my) || (v.x == my && (k + 0) < i);
    r1 += (v.y < my) || (v.y == my && (k + 1) < i);
    r2 += (v.z < my) || (v.z == my && (k + 2) < i);
    r3 += (v.w < my) || (v.w == my && (k + 3) < i);
  }
  partials[row][chunk] = (r0 + r1) + (r2 + r3);
  __syncthreads();
  if (tid < 32) {                    // one thread per row: finalize + scatter
    int rank = 0;
#pragma unroll
    for (int c = 0; c < 32; ++c) rank += partials[tid][c];
    const int ii = (rg << 5) + tid;
    ws[OFF_Q + (b << 12) + rank] = lp[ii];
    ((int*)ws)[OFF_PERM + (b << 12) + rank] = ii;
  }
}

//========== K34: fused prefix structures (replaces K3+K4) ====================
// grid B*32: b = bid>>5, cg = bid&31 owns chunks {2cg, 2cg+1}; 1024 threads.
// Phase A: full-batch e1/e2 arrays in LDS + chunk scalar sums -> PreS/SufS
//          for this block's 128 k's (shfl scans; sentinels by cg 0/31).
// Phase B: redundant full-batch weighted chunk sums S1L/S2L[64][64] in LDS
//          (each thread owns one (chunk, o4); gathers ~1 MB of L2-warm gx).
// Phase C: chunk offsets from S-LDS, intra-chunk prefixes, PreG/SufG writes
//          (identical math/order to old K4).
// Static LDS pinned at exactly 64 KB via phase aliasing inside S1L.
__global__ __launch_bounds__(1024) void k34_prefix(float* __restrict__ ws) {
  __shared__ float smem[16384];                 // 64 KB
  float* le1 = smem;                            // e^q       [4096]
  float* le2 = smem + 4096;                     // e^{0.2q}  [4096]
  float* S1L = smem + 8192;                     // [64][64] e1-weighted chunk sums
  float* S2L = smem + 12288;                    // [64][64] e2-weighted chunk sums
  // phase-A aliases (dead before phase B writes S1L):
  float* cs1  = S1L;                            // [64] chunk scalar sums e1
  float* cs2  = S1L + 64;                       // [64] chunk scalar sums e2
  float* cum1 = S1L + 128;                      // [64] exclusive chunk prefix e1
  float* cum2 = S1L + 192;                      // [64] exclusive chunk prefix e2
  float* tots = S1L + 256;                      // [0]=tot1 [1]=tot2
  const int tid = threadIdx.x;
  const int b = blockIdx.x >> 5, cg = blockIdx.x & 31;
  const float* q = ws + OFF_Q + (b << 12);
  // ---- A1: e-arrays + per-chunk scalar sums (16 threads per 64-k chunk) ----
  const float4 q4 = ((const float4*)q)[tid];
  const float e1r0 = expf(q4.x), e1r1 = expf(q4.y), e1r2 = expf(q4.z), e1r3 = expf(q4.w);
  const float e2r0 = expf(0.2f * q4.x), e2r1 = expf(0.2f * q4.y),
              e2r2 = expf(0.2f * q4.z), e2r3 = expf(0.2f * q4.w);
  const int k4 = tid << 2;
  float4 t1v = {e1r0, e1r1, e1r2, e1r3};
  float4 t2v = {e2r0, e2r1, e2r2, e2r3};
  *(float4*)&le1[k4] = t1v;
  *(float4*)&le2[k4] = t2v;
  float s1 = (e1r0 + e1r1) + (e1r2 + e1r3);
  float s2 = (e2r0 + e2r1) + (e2r2 + e2r3);
  for (int off = 8; off; off >>= 1) {           // reduce within 16-lane groups
    s1 += __shfl_down(s1, off, 16);
    s2 += __shfl_down(s2, off, 16);
  }
  if ((tid & 15) == 0) { cs1[tid >> 4] = s1; cs2[tid >> 4] = s2; }
  __syncthreads();
  // ---- A2: chunk-level exclusive prefixes (wave 0, broadcast reads) ----
  if (tid < 64) {
    float a1s = 0.f, a2s = 0.f;
    for (int c2 = 0; c2 < 64; ++c2) {
      float v1 = cs1[c2], v2 = cs2[c2];
      a1s += (c2 < tid) ? v1 : 0.f;
      a2s += (c2 < tid) ? v2 : 0.f;
    }
    cum1[tid] = a1s; cum2[tid] = a2s;
    if (tid == 63) { tots[0] = a1s + cs1[63]; tots[1] = a2s + cs2[63]; }
  }
  __syncthreads();
  // ---- A3: PreS/SufS for this block's 128 k's (one wave per chunk) ----
  if (tid < 128) {
    const int k = (cg << 7) + tid, c = k >> 6, lane = tid & 63;
    float x1 = le1[k], x2 = le2[k];
    const float e1v = x1, e2v = x2;
    for (int off = 1; off < 64; off <<= 1) {
      float u1 = __shfl_up(x1, off, 64);
      float u2 = __shfl_up(x2, off, 64);
      if (lane >= off) { x1 += u1; x2 += u2; }
    }
    ws[OFF_PRES + b * NS + k] = cum2[c] + (x2 - e2v);                  // excl prefix e2
    ws[OFF_SUFS + b * NS + k] = tots[0] - (cum1[c] + (x1 - e1v));      // incl suffix e1
    if (cg == 31 && tid == 127) ws[OFF_PRES + b * NS + N] = tots[1];   // tot2
    if (cg == 0 && tid == 0)    ws[OFF_SUFS + b * NS + N] = 0.f;
  }
  __syncthreads();   // cs/cum/tots dead -> S1L/S2L free for phase B
  // ---- B: redundant full-batch weighted chunk sums ----
  const int l16 = tid & 15, krow = tid >> 4;    // krow = chunk 0..63
  const int* perm = (const int*)ws + OFF_PERM + (b << 12);
  const float* gx = ws + OFF_GX + ((size_t)b << 18);
  float4 a1 = {0.f, 0.f, 0.f, 0.f}, a2 = {0.f, 0.f, 0.f, 0.f};
  const int kb = krow << 6;
  const int jrot = (krow & 3) << 4;             // 2-bank (free) LDS broadcast
  for (int jj = 0; jj < 64; ++jj) {
    const int k = kb + ((jj + jrot) & 63);
    const float4 g = *(const float4*)(gx + ((size_t)perm[k] << 6) + (l16 << 2));
    const float e1 = le1[k], e2 = le2[k];
    a1.x += e1 * g.x; a1.y += e1 * g.y; a1.z += e1 * g.z; a1.w += e1 * g.w;
    a2.x += e2 * g.x; a2.y += e2 * g.y; a2.z += e2 * g.z; a2.w += e2 * g.w;
  }
  *(float4*)&S1L[(krow << 6) + (l16 << 2)] = a1;
  *(float4*)&S2L[(krow << 6) + (l16 << 2)] = a2;
  __syncthreads();
  // ---- C: chunk offsets (both chunks up-front; S dies after), PreG/SufG ----
  const int o = tid & 63, kk = tid >> 6;
  const int c0 = cg << 1;
  float op0 = 0.f, os0 = 0.f, op1 = 0.f, os1 = 0.f;
  for (int cc = 0; cc < 64; ++cc) {
    const float v2 = S2L[(cc << 6) + o];
    const float v1 = S1L[(cc << 6) + o];
    op0 += (cc < c0) ? v2 : 0.f;       os0 += (cc > c0) ? v1 : 0.f;
    op1 += (cc <= c0) ? v2 : 0.f;      os1 += (cc > c0 + 1) ? v1 : 0.f;
  }
  __syncthreads();                     // S region dead -> sA/sB alias
  float* sA = S1L;                     // [16][64]
  float* sB = S1L + 1024;              // [16][64]
  float* PreG = ws + OFF_PREG + (size_t)b * NR * 64;
  float* SufG = ws + OFF_SUFG + (size_t)b * NR * 64;
#pragma unroll
  for (int ci = 0; ci < 2; ++ci) {
    const int c = c0 + ci;
    const int k0 = (c << 6) + (kk << 2);
    float w1[4], w2[4];
    float p1 = 0.f, p2 = 0.f;
#pragma unroll
    for (int r = 0; r < 4; ++r) {
      const int k = k0 + r;
      const float g = gx[((size_t)perm[k] << 6) + o];   // coalesced row gather
      w1[r] = le1[k] * g;
      w2[r] = le2[k] * g;
      p1 += w1[r]; p2 += w2[r];
    }
    sA[(kk << 6) + o] = p2;
    sB[(kk << 6) + o] = p1;
    __syncthreads();
    float op = ci ? op1 : op0;
    float os = ci ? os1 : os0;
    for (int kp = 0; kp < kk; ++kp) op += sA[(kp << 6) + o];
    for (int kp = kk + 1; kp < 16; ++kp) os += sB[(kp << 6) + o];
    float run = op;                    // exclusive prefix
#pragma unroll
    for (int r = 0; r < 4; ++r) { PreG[(size_t)(k0 + r) * 64 + o] = run; run += w2[r]; }
    if (c == 63 && kk == 15) PreG[(size_t)N * 64 + o] = run;   // grand total
    run = os;                          // inclusive suffix
#pragma unroll
    for (int r = 3; r >= 0; --r) { run += w1[r]; SufG[(size_t)(k0 + r) * 64 + o] = run; }
    if (c == 0 && kk == 0) SufG[(size_t)N * 64 + o] = 0.f;
    __syncthreads();                   // sA/sB reused by next ci
  }
}

//========== K5: per-row threshold lookup + output; gated C_k fallback ========
__global__ __launch_bounds__(1024) void k5_out(const float* __restrict__ Ck,
                                               float* __restrict__ ws,
                                               float* __restrict__ y) {
  __shared__ float lq[N];
  const int tid = threadIdx.x;
  const int b = blockIdx.x >> 6, rg = blockIdx.x & 63;   // 64 rows per block
  const float4* qs = (const float4*)(ws + OFF_Q + b * N);
  ((float4*)lq)[tid] = qs[tid];
  __syncthreads();
  const int io = tid & 63, og = tid >> 6;   // 16 threads/row, 4 o's each
  const int i = (rg << 6) + io;
  float ai = ws[OFF_A + (b << 12) + i];
  float thr = -ai;
  int lo = 0, hi = N;
  while (lo < hi) { int m = (lo + hi) >> 1; if (lq[m] <= thr) lo = m + 1; else hi = m; }
  const int k = lo;  // first index with q > -a_i
  float e1 = expf(ai), e2 = expf(0.2f * ai);
  float den = e1 * ws[OFF_SUFS + b * NS + k] + e2 * ws[OFF_PRES + b * NS + k];
  float inv = 1.0f / den;
  float4 pv = ((const float4*)(ws + OFF_PREG + ((size_t)b * NR + k) * 64))[og];
  float4 sv = ((const float4*)(ws + OFF_SUFG + ((size_t)b * NR + k) * 64))[og];
  float* yb = y + ((size_t)((b << 6) + (og << 2))) * N + i;
  yb[0]             = (e1 * sv.x + e2 * pv.x) * inv;
  yb[(size_t)N]     = (e1 * sv.y + e2 * pv.y) * inv;
  yb[(size_t)2 * N] = (e1 * sv.z + e2 * pv.z) * inv;
  yb[(size_t)3 * N] = (e1 * sv.w + e2 * pv.w) * inv;
  // ---- gated fallback y += C_k @ g_x (never taken in this harness) ----
  if (((const volatile int*)ws)[OFF_FLAG] == MAGIC) {
    __syncthreads();
    const int it = rg;                        // 64 rows per block
    const int o = tid & 63, jj = tid >> 6;    // 16 j-stripes
    const float* gx = ws + OFF_GX + ((size_t)b << 18);
    float (*red)[64] = (float(*)[64])lq;      // reuse LDS
    for (int ii = 0; ii < 64; ++ii) {
      int irow = (it << 6) + ii;
      float acc = 0.f;
      for (int j = jj; j < N; j += 16)
        acc += Ck[(size_t)irow * N + j] * gx[((size_t)j << 6) + o];
      red[jj][o] = acc;
      __syncthreads();
      if (jj == 0) {
        float s = 0.f;
#pragma unroll
        for (int g = 0; g < 16; ++g) s += red[g][o];
        y[((size_t)((b << 6) + o)) * N + irow] += s;
      }
      __syncthreads();
    }
  }
}

extern "C" void kernel_launch(void* const* d_in, const int* in_sizes, int n_in,
                              void* d_out, int out_size, void* d_ws, size_t ws_size,
                              hipStream_t stream) {
  (void)in_sizes; (void)n_in; (void)out_size; (void)ws_size;
  const float* x       = (const float*)d_in[0];
  const float* g_w     = (const float*)d_in[1];
  const float* g_b     = (const float*)d_in[2];
  const float* theta_w = (const float*)d_in[3];
  const float* theta_b = (const float*)d_in[4];
  const float* phi_w   = (const float*)d_in[5];
  const float* phi_b   = (const float*)d_in[6];
  const float* cp_w    = (const float*)d_in[7];
  const float* Ck      = (const float*)d_in[8];
  float* ws = (float*)d_ws;
  float* y  = (float*)d_out;

  hipLaunchKernelGGL(k1_gx, dim3(1024), dim3(256), 0, stream,
                     x, g_w, g_b, theta_w, theta_b, phi_w, phi_b, cp_w, Ck, ws);
  hipLaunchKernelGGL(k2_rank, dim3(512), dim3(1024), 0, stream, ws);
  hipLaunchKernelGGL(k34_prefix, dim3(B * 32), dim3(1024), 0, stream, ws);
  hipLaunchKernelGGL(k5_out, dim3(B * 64), dim3(1024), 0, stream, Ck, ws, y);
}

// Round 2
// 150.241 us; speedup vs baseline: 1.0769x; 1.0769x over previous
//
#include <hip/hip_runtime.h>

// GlobalGraphConv: B=4, C=64, N=4096, IC=32
// f[i,j] = a_i + p_j (outer sum); lrelu piecewise-linear =>
// exp(lrelu(a_i+p_j)) factorizes per branch; sort p, softmax row = threshold
// lookup into prefix/suffix sums of weighted g_x rows. O(N^2 C) -> O(N C).
// R10: revert R9's K34 fusion (redundant-gather fusion lost ~20us vs the
// ~9us boundary it saved). Back to the proven R8 5-dispatch pipeline, with
// ONE change: the mandatory 67 MB C_k zero-scan (10.6us of HBM) is split
// into four 16.8 MB quarters, one per dispatch K1..K4, so it hides under
// each kernel's compute/latency instead of serializing inside K1.

#define B  4
#define C  64
#define N  4096
#define IC 32
#define NS 4104   // per-batch stride for PreS/SufS (>= N+1)
#define NR 4097   // rows per batch for PreG/SufG (k = 0..N)
#define MAGIC 0x13572468
#define CKQ 1048576   // C_k quarter size in float4 (N*N/4/4)

// workspace offsets (in floats)
#define OFF_FLAG   248          // int: C_k nonzero marker (MAGIC if nonzero)
#define OFF_A      256
#define OFF_P      (OFF_A + B*N)
#define OFF_Q      (OFF_P + B*N)
#define OFF_PERM   (OFF_Q + B*N)            // ints
#define OFF_PRES   (OFF_PERM + B*N)
#define OFF_SUFS   (OFF_PRES + B*NS)
#define OFF_S1     (OFF_SUFS + B*NS)        // chunk sums (e^q-weighted) B*64*64
#define OFF_S2     (OFF_S1 + B*64*64)       // chunk sums (e^{0.2q}) B*64*64
#define OFF_GX     (OFF_S2 + B*64*64)       // B*N*64, layout [b][n][o]
#define OFF_PREG   (OFF_GX + B*N*64)        // B*NR*64, layout [b][k][o]
#define OFF_SUFG   (OFF_PREG + B*NR*64)

#define CK_NZ(v) ((v.x != 0.f) | (v.y != 0.f) | (v.z != 0.f) | (v.w != 0.f))

//========== K1: gx = g_w@x + g_b; a,p; + C_k scan quarter 0 ==================
__global__ __launch_bounds__(256) void k1_gx(
    const float* __restrict__ x, const float* __restrict__ g_w,
    const float* __restrict__ g_b, const float* __restrict__ theta_w,
    const float* __restrict__ theta_b, const float* __restrict__ phi_w,
    const float* __restrict__ phi_b, const float* __restrict__ cp_w,
    const float* __restrict__ Ck, float* __restrict__ ws) {
  __shared__ float gwT[C * C];   // [cc][o]
  __shared__ float xl[C * 16];   // [cc][nn]
  __shared__ float lu[C], lv[C], cst[2];
  const int tid = threadIdx.x;
  const int b = blockIdx.x >> 8;           // 256 blocks per batch
  const int n0 = (blockIdx.x & 255) << 4;  // 16 nodes per block
  // ---- C_k scan quarter 0: issue loads first, they fly under the LDS work
  const float4* c4 = (const float4*)Ck;
  float4 ck0, ck1, ck2, ck3;
  {
    int idx = (blockIdx.x << 8) + tid;     // 262144 threads, 4 f4 each
    ck0 = c4[idx]; ck1 = c4[idx + 262144];
    ck2 = c4[idx + 524288]; ck3 = c4[idx + 786432];
  }
  for (int idx = tid; idx < C * C; idx += 256) {
    int o = idx >> 6, cc = idx & 63;
    gwT[cc * C + o] = g_w[idx];
  }
  for (int idx = tid; idx < C * 16; idx += 256) {
    int cc = idx >> 4, nn = idx & 15;
    xl[idx] = x[(size_t)((b << 6) + cc) * N + n0 + nn];
  }
  if (tid < 64) {
    float u = 0.f;
    for (int k = 0; k < IC; ++k) u += cp_w[k] * theta_w[k * C + tid];
    lu[tid] = u;
  } else if (tid < 128) {
    int c = tid - 64;
    float v = 0.f;
    for (int k = 0; k < IC; ++k) v += cp_w[IC + k] * phi_w[k * C + c];
    lv[c] = v;
  } else if (tid == 128) {
    float ca = 0.f, cp2 = 0.f;
    for (int k = 0; k < IC; ++k) { ca += cp_w[k] * theta_b[k]; cp2 += cp_w[IC + k] * phi_b[k]; }
    cst[0] = ca; cst[1] = cp2;
  }
  __syncthreads();
  if (tid < 16) {   // a,p: one thread per node
    float au = cst[0], pu = cst[1];
    for (int cc = 0; cc < C; ++cc) {
      float xv = xl[cc * 16 + tid];
      au += lu[cc] * xv;
      pu += lv[cc] * xv;
    }
    ws[OFF_A + (b << 12) + n0 + tid] = au;
    ws[OFF_P + (b << 12) + n0 + tid] = pu;
  }
  const int o = tid & 63, g4 = tid >> 6;
  float bb = g_b[o];
  float acc0 = bb, acc1 = bb, acc2 = bb, acc3 = bb;
  for (int cc = 0; cc < C; ++cc) {
    float gv = gwT[cc * C + o];                 // stride-1: conflict-free
    const float* xr = &xl[cc * 16 + (g4 << 2)]; // wave broadcast
    acc0 += gv * xr[0]; acc1 += gv * xr[1]; acc2 += gv * xr[2]; acc3 += gv * xr[3];
  }
  float* gx = ws + OFF_GX + (size_t)((b << 12) + n0 + (g4 << 2)) * C + o;
  gx[0] = acc0; gx[64] = acc1; gx[128] = acc2; gx[192] = acc3;
  bool nz = CK_NZ(ck0) | CK_NZ(ck1) | CK_NZ(ck2) | CK_NZ(ck3);
  if (__any(nz) && (tid & 63) == 0)
    atomicExch((int*)ws + OFF_FLAG, MAGIC);
}

//========== K2: rank-by-counting + scatter; + C_k scan quarter 1 =============
// grid 512: b = bid>>7, 128 blocks/batch, 32 rows each; 1024 thr = 32r x 32c
__global__ __launch_bounds__(1024) void k2_rank(const float* __restrict__ Ck,
                                                float* __restrict__ ws) {
  __shared__ float lp[N];            // 16 KB: full batch p
  __shared__ int partials[32][33];   // +1 pad
  const int tid = threadIdx.x;
  const int b = blockIdx.x >> 7;
  const int rg = blockIdx.x & 127;
  // ---- C_k scan quarter 1 (loads issued early, consumed at the end) ----
  const float4* c4 = (const float4*)Ck + CKQ;
  float4 ck0, ck1;
  {
    int idx = (blockIdx.x << 10) + tid;   // 524288 threads, 2 f4 each
    ck0 = c4[idx]; ck1 = c4[idx + 524288];
  }
  const float* p = ws + OFF_P + b * N;
  ((float4*)lp)[tid] = ((const float4*)p)[tid];
  const int row = tid & 31, chunk = tid >> 5;
  const int i = (rg << 5) + row;     // batch-local row index
  __syncthreads();
  const float my = lp[i];
  const int c0 = chunk << 7;         // 128 cols per chunk
  const float4* lp4 = (const float4*)(lp + c0);
  int r0 = 0, r1 = 0, r2 = 0, r3 = 0;
  for (int j = 0; j < 32; ++j) {
    float4 v = lp4[j];               // 2 addrs/wave: free 2-way broadcast
    int k = c0 + (j << 2);
    r0 += (v.x < my) || (v.x == my && (k + 0) < i);
    r1 += (v.y < my) || (v.y == my && (k + 1) < i);
    r2 += (v.z < my) || (v.z == my && (k + 2) < i);
    r3 += (v.w < my) || (v.w == my && (k + 3) < i);
  }
  partials[row][chunk] = (r0 + r1) + (r2 + r3);
  __syncthreads();
  if (tid < 32) {                    // one thread per row: finalize + scatter
    int rank = 0;
#pragma unroll
    for (int c = 0; c < 32; ++c) rank += partials[tid][c];
    const int ii = (rg << 5) + tid;
    ws[OFF_Q + (b << 12) + rank] = lp[ii];
    ((int*)ws)[OFF_PERM + (b << 12) + rank] = ii;
  }
  bool nz = CK_NZ(ck0) | CK_NZ(ck1);
  if (__any(nz) && (tid & 63) == 0)
    atomicExch((int*)ws + OFF_FLAG, MAGIC);
}

//========== K3: blocks 0-3 scalar scans; blocks 4.. D1 chunk sums ============
// + C_k scan quarter 2
__global__ __launch_bounds__(1024) void k3_scan_chunks(const float* __restrict__ Ck,
                                                       float* __restrict__ ws) {
  __shared__ float sA[1024], sB[1024];
  const int tid = threadIdx.x;
  const int bid = blockIdx.x;
  // ---- C_k scan quarter 2 (266240 threads, 4 f4 grid-strided, bounded) ----
  const float4* c4 = (const float4*)Ck + 2 * CKQ;
  float4 ck0 = {0.f,0.f,0.f,0.f}, ck1 = ck0, ck2 = ck0, ck3 = ck0;
  {
    int idx = (bid << 10) + tid;
    if (idx < CKQ) ck0 = c4[idx];  idx += 266240;
    if (idx < CKQ) ck1 = c4[idx];  idx += 266240;
    if (idx < CKQ) ck2 = c4[idx];  idx += 266240;
    if (idx < CKQ) ck3 = c4[idx];
  }
  if (bid < B) {
    // ---- PreS/SufS shuffle scans (R7-proven) ----
    const int b = bid;
    float* wt2 = sA;        // 16
    float* wt1 = sA + 16;   // 16
    float* wo2 = sA + 32;   // 17
    float* wo1 = sA + 49;   // 17
    const float* q = ws + OFF_Q + b * N;
    const float4 qv4 = ((const float4*)q)[tid];
    float e1r[4], e2r[4];
    e2r[0] = expf(0.2f * qv4.x); e1r[0] = expf(qv4.x);
    e2r[1] = expf(0.2f * qv4.y); e1r[1] = expf(qv4.y);
    e2r[2] = expf(0.2f * qv4.z); e1r[2] = expf(qv4.z);
    e2r[3] = expf(0.2f * qv4.w); e1r[3] = expf(qv4.w);
    float s2 = e2r[0] + e2r[1] + e2r[2] + e2r[3];
    float s1 = e1r[0] + e1r[1] + e1r[2] + e1r[3];
    const int lane = tid & 63, wave = tid >> 6;   // 16 waves
    float x2 = s2, x1 = s1;
    for (int off = 1; off < 64; off <<= 1) {
      float t2 = __shfl_up(x2, off, 64);
      float t1 = __shfl_up(x1, off, 64);
      if (lane >= off) { x2 += t2; x1 += t1; }
    }
    if (lane == 63) { wt2[wave] = x2; wt1[wave] = x1; }
    __syncthreads();
    if (wave == 0 && lane < 17) {
      float a2 = 0.f, a1 = 0.f;
      for (int w = 0; w < 16; ++w) {
        if (w < lane) { a2 += wt2[w]; a1 += wt1[w]; }
      }
      wo2[lane] = a2; wo1[lane] = a1;   // wo[16] = grand totals
    }
    __syncthreads();
    const float excl2 = wo2[wave] + (x2 - s2);
    const float incl1 = wo1[wave] + x1;
    const float tot1 = wo1[16];
    float* PreS = ws + OFF_PRES + b * NS;
    float* SufS = ws + OFF_SUFS + b * NS;
    const int base = tid << 2;
    float run = excl2;
#pragma unroll
    for (int j = 0; j < 4; ++j) { PreS[base + j] = run; run += e2r[j]; }
    if (tid == 1023) PreS[N] = run;
    run = tot1 - incl1;
#pragma unroll
    for (int j = 3; j >= 0; --j) { run += e1r[j]; SufS[base + j] = run; }
    if (tid == 1023) SufS[N] = 0.f;
  } else {
    // ---- D1: per-chunk (64 k's) weighted g_x sums (R6-proven) ----
    const int b2 = bid - B;
    const int b = b2 >> 6, c = b2 & 63;
    const int o = tid & 63, kk = tid >> 6;
    const float* q = ws + OFF_Q + b * N;
    const int* perm = (const int*)ws + OFF_PERM + b * N;
    const float* gx = ws + OFF_GX + ((size_t)b << 18);
    float p1 = 0.f, p2 = 0.f;
    const int k0 = (c << 6) + (kk << 2);
    for (int r = 0; r < 4; ++r) {
      int k = k0 + r;
      float qv = q[k];
      float g = gx[((size_t)perm[k] << 6) + o];   // coalesced row gather
      p1 += expf(qv) * g;
      p2 += expf(0.2f * qv) * g;
    }
    sA[(kk << 6) + o] = p2;
    sB[(kk << 6) + o] = p1;
    __syncthreads();
    if (tid < 64) {
      float t2 = 0.f, t1 = 0.f;
#pragma unroll
      for (int g = 0; g < 16; ++g) { t2 += sA[(g << 6) + o]; t1 += sB[(g << 6) + o]; }
      ws[OFF_S2 + (size_t)(((b << 6) + c) << 6) + o] = t2;
      ws[OFF_S1 + (size_t)(((b << 6) + c) << 6) + o] = t1;
    }
  }
  bool nz = CK_NZ(ck0) | CK_NZ(ck1) | CK_NZ(ck2) | CK_NZ(ck3);
  if (__any(nz) && (tid & 63) == 0)
    atomicExch((int*)ws + OFF_FLAG, MAGIC);
}

//========== K4: D3 redundant chunk offsets + final PreG/SufG =================
// + C_k scan quarter 3
__global__ __launch_bounds__(1024) void k4_prefix(const float* __restrict__ Ck,
                                                  float* __restrict__ ws) {
  __shared__ float sA[1024], sB[1024];
  const int tid = threadIdx.x;
  const int b = blockIdx.x >> 6, c = blockIdx.x & 63;
  const int o = tid & 63, kk = tid >> 6;
  // ---- C_k scan quarter 3 (262144 threads, 4 f4 each) ----
  const float4* c4 = (const float4*)Ck + 3 * CKQ;
  float4 ck0, ck1, ck2, ck3;
  {
    int idx = (blockIdx.x << 10) + tid;
    ck0 = c4[idx]; ck1 = c4[idx + 262144];
    ck2 = c4[idx + 524288]; ck3 = c4[idx + 786432];
  }
  float offp = 0.f, offs = 0.f;
  {
    const float* S1 = ws + OFF_S1 + ((size_t)b << 12);
    const float* S2 = ws + OFF_S2 + ((size_t)b << 12);
    for (int cc = 0; cc < 64; ++cc) {
      float v2 = S2[(cc << 6) + o];
      float v1 = S1[(cc << 6) + o];
      offp += (cc < c) ? v2 : 0.f;
      offs += (cc > c) ? v1 : 0.f;
    }
  }
  const float* q = ws + OFF_Q + b * N;
  const int* perm = (const int*)ws + OFF_PERM + b * N;
  const float* gx = ws + OFF_GX + ((size_t)b << 18);
  float* PreG = ws + OFF_PREG + (size_t)b * NR * 64;
  float* SufG = ws + OFF_SUFG + (size_t)b * NR * 64;
  const int k0 = (c << 6) + (kk << 2);
  float w1[4], w2[4];
  float p1 = 0.f, p2 = 0.f;
  for (int r = 0; r < 4; ++r) {
    float qq = q[k0 + r];
    float gg = gx[((size_t)perm[k0 + r] << 6) + o];
    w1[r] = expf(qq) * gg;
    w2[r] = expf(0.2f * qq) * gg;
    p1 += w1[r]; p2 += w2[r];
  }
  sA[(kk << 6) + o] = p2;
  sB[(kk << 6) + o] = p1;
  __syncthreads();
  for (int kp = 0; kp < kk; ++kp) offp += sA[(kp << 6) + o];
  for (int kp = kk + 1; kp < 16; ++kp) offs += sB[(kp << 6) + o];
  float run = offp;          // exclusive prefix
#pragma unroll
  for (int r = 0; r < 4; ++r) { PreG[(size_t)(k0 + r) * 64 + o] = run; run += w2[r]; }
  if (c == 63 && kk == 15) PreG[(size_t)N * 64 + o] = run;   // grand total
  run = offs;                // inclusive suffix
#pragma unroll
  for (int r = 3; r >= 0; --r) { run += w1[r]; SufG[(size_t)(k0 + r) * 64 + o] = run; }
  if (c == 0 && kk == 0) SufG[(size_t)N * 64 + o] = 0.f;
  bool nz = CK_NZ(ck0) | CK_NZ(ck1) | CK_NZ(ck2) | CK_NZ(ck3);
  if (__any(nz) && (tid & 63) == 0)
    atomicExch((int*)ws + OFF_FLAG, MAGIC);
}

//========== K5: per-row threshold lookup + output; gated C_k fallback ========
__global__ __launch_bounds__(1024) void k5_out(const float* __restrict__ Ck,
                                               float* __restrict__ ws,
                                               float* __restrict__ y) {
  __shared__ float lq[N];
  const int tid = threadIdx.x;
  const int b = blockIdx.x >> 6, rg = blockIdx.x & 63;   // 64 rows per block
  const float4* qs = (const float4*)(ws + OFF_Q + b * N);
  ((float4*)lq)[tid] = qs[tid];
  __syncthreads();
  const int io = tid & 63, og = tid >> 6;   // 16 threads/row, 4 o's each
  const int i = (rg << 6) + io;
  float ai = ws[OFF_A + (b << 12) + i];
  float thr = -ai;
  int lo = 0, hi = N;
  while (lo < hi) { int m = (lo + hi) >> 1; if (lq[m] <= thr) lo = m + 1; else hi = m; }
  const int k = lo;  // first index with q > -a_i
  float e1 = expf(ai), e2 = expf(0.2f * ai);
  float den = e1 * ws[OFF_SUFS + b * NS + k] + e2 * ws[OFF_PRES + b * NS + k];
  float inv = 1.0f / den;
  float4 pv = ((const float4*)(ws + OFF_PREG + ((size_t)b * NR + k) * 64))[og];
  float4 sv = ((const float4*)(ws + OFF_SUFG + ((size_t)b * NR + k) * 64))[og];
  float* yb = y + ((size_t)((b << 6) + (og << 2))) * N + i;
  yb[0]             = (e1 * sv.x + e2 * pv.x) * inv;
  yb[(size_t)N]     = (e1 * sv.y + e2 * pv.y) * inv;
  yb[(size_t)2 * N] = (e1 * sv.z + e2 * pv.z) * inv;
  yb[(size_t)3 * N] = (e1 * sv.w + e2 * pv.w) * inv;
  // ---- gated fallback y += C_k @ g_x (never taken in this harness) ----
  if (((const volatile int*)ws)[OFF_FLAG] == MAGIC) {
    __syncthreads();
    const int it = rg;                        // 64 rows per block
    const int o = tid & 63, jj = tid >> 6;    // 16 j-stripes
    const float* gx = ws + OFF_GX + ((size_t)b << 18);
    float (*red)[64] = (float(*)[64])lq;      // reuse LDS
    for (int ii = 0; ii < 64; ++ii) {
      int irow = (it << 6) + ii;
      float acc = 0.f;
      for (int j = jj; j < N; j += 16)
        acc += Ck[(size_t)irow * N + j] * gx[((size_t)j << 6) + o];
      red[jj][o] = acc;
      __syncthreads();
      if (jj == 0) {
        float s = 0.f;
#pragma unroll
        for (int g = 0; g < 16; ++g) s += red[g][o];
        y[((size_t)((b << 6) + o)) * N + irow] += s;
      }
      __syncthreads();
    }
  }
}

extern "C" void kernel_launch(void* const* d_in, const int* in_sizes, int n_in,
                              void* d_out, int out_size, void* d_ws, size_t ws_size,
                              hipStream_t stream) {
  (void)in_sizes; (void)n_in; (void)out_size; (void)ws_size;
  const float* x       = (const float*)d_in[0];
  const float* g_w     = (const float*)d_in[1];
  const float* g_b     = (const float*)d_in[2];
  const float* theta_w = (const float*)d_in[3];
  const float* theta_b = (const float*)d_in[4];
  const float* phi_w   = (const float*)d_in[5];
  const float* phi_b   = (const float*)d_in[6];
  const float* cp_w    = (const float*)d_in[7];
  const float* Ck      = (const float*)d_in[8];
  float* ws = (float*)d_ws;
  float* y  = (float*)d_out;

  hipLaunchKernelGGL(k1_gx, dim3(1024), dim3(256), 0, stream,
                     x, g_w, g_b, theta_w, theta_b, phi_w, phi_b, cp_w, Ck, ws);
  hipLaunchKernelGGL(k2_rank, dim3(512), dim3(1024), 0, stream, Ck, ws);
  hipLaunchKernelGGL(k3_scan_chunks, dim3(B + B * 64), dim3(1024), 0, stream, Ck, ws);
  hipLaunchKernelGGL(k4_prefix, dim3(B * 64), dim3(1024), 0, stream, Ck, ws);
  hipLaunchKernelGGL(k5_out, dim3(B * 64), dim3(1024), 0, stream, Ck, ws, y);
}

// Round 3
// 147.393 us; speedup vs baseline: 1.0977x; 1.0193x over previous
//
#include <hip/hip_runtime.h>

// GlobalGraphConv: B=4, C=64, N=4096, IC=32
// f[i,j] = a_i + p_j (outer sum); lrelu piecewise-linear =>
// exp(lrelu(a_i+p_j)) factorizes per branch; sort p, softmax row = threshold
// lookup into prefix/suffix sums of weighted g_x rows. O(N^2 C) -> O(N C).
// R11: 5 -> 4 dispatches with STRICTLY LESS work (unlike R9's redundant
// fusion). Insight: K4's within-chunk prefixes depend only on K2's output;
// only the cross-chunk offset sweep needed K3's chunk sums. So:
//  - K34: scalar scans (blocks 0-3) || local prefixes (blocks 4-259), which
//    also emit chunk totals from their own sA/sB partials -> old K3-D1's
//    256 blocks of gather+exp are deleted (K4 used to re-gather them too).
//  - K5: stages S1/S2 (32KB, L2-hot), two-level parallel chunk scan in LDS,
//    composes global = cum[chunk] + local[k]. Same sweep K4 did, relocated.

#define B  4
#define C  64
#define N  4096
#define IC 32
#define NS 4104   // per-batch stride for PreS/SufS (>= N+1)
#define NR 4097   // rows per batch for PreG/SufG (k = 0..N; row N unused now)
#define MAGIC 0x13572468
#define CKQ 1048576   // C_k quarter size in float4 (N*N/4/4)

// workspace offsets (in floats)
#define OFF_FLAG   248          // int: C_k nonzero marker (MAGIC if nonzero)
#define OFF_A      256
#define OFF_P      (OFF_A + B*N)
#define OFF_Q      (OFF_P + B*N)
#define OFF_PERM   (OFF_Q + B*N)            // ints
#define OFF_PRES   (OFF_PERM + B*N)
#define OFF_SUFS   (OFF_PRES + B*NS)
#define OFF_S1     (OFF_SUFS + B*NS)        // chunk sums (e^q-weighted) B*64*64
#define OFF_S2     (OFF_S1 + B*64*64)       // chunk sums (e^{0.2q}) B*64*64
#define OFF_GX     (OFF_S2 + B*64*64)       // B*N*64, layout [b][n][o]
#define OFF_PREG   (OFF_GX + B*N*64)        // B*NR*64, layout [b][k][o] (LOCAL)
#define OFF_SUFG   (OFF_PREG + B*NR*64)     // (LOCAL within-chunk)

#define CK_NZ(v) ((v.x != 0.f) | (v.y != 0.f) | (v.z != 0.f) | (v.w != 0.f))

//========== K1: gx = g_w@x + g_b; a,p; + C_k scan quarter 0 ==================
__global__ __launch_bounds__(256) void k1_gx(
    const float* __restrict__ x, const float* __restrict__ g_w,
    const float* __restrict__ g_b, const float* __restrict__ theta_w,
    const float* __restrict__ theta_b, const float* __restrict__ phi_w,
    const float* __restrict__ phi_b, const float* __restrict__ cp_w,
    const float* __restrict__ Ck, float* __restrict__ ws) {
  __shared__ float gwT[C * C];   // [cc][o]
  __shared__ float xl[C * 16];   // [cc][nn]
  __shared__ float lu[C], lv[C], cst[2];
  const int tid = threadIdx.x;
  const int b = blockIdx.x >> 8;           // 256 blocks per batch
  const int n0 = (blockIdx.x & 255) << 4;  // 16 nodes per block
  // ---- C_k scan quarter 0: issue loads first, they fly under the LDS work
  const float4* c4 = (const float4*)Ck;
  float4 ck0, ck1, ck2, ck3;
  {
    int idx = (blockIdx.x << 8) + tid;     // 262144 threads, 4 f4 each
    ck0 = c4[idx]; ck1 = c4[idx + 262144];
    ck2 = c4[idx + 524288]; ck3 = c4[idx + 786432];
  }
  for (int idx = tid; idx < C * C; idx += 256) {
    int o = idx >> 6, cc = idx & 63;
    gwT[cc * C + o] = g_w[idx];
  }
  for (int idx = tid; idx < C * 16; idx += 256) {
    int cc = idx >> 4, nn = idx & 15;
    xl[idx] = x[(size_t)((b << 6) + cc) * N + n0 + nn];
  }
  if (tid < 64) {
    float u = 0.f;
    for (int k = 0; k < IC; ++k) u += cp_w[k] * theta_w[k * C + tid];
    lu[tid] = u;
  } else if (tid < 128) {
    int c = tid - 64;
    float v = 0.f;
    for (int k = 0; k < IC; ++k) v += cp_w[IC + k] * phi_w[k * C + c];
    lv[c] = v;
  } else if (tid == 128) {
    float ca = 0.f, cp2 = 0.f;
    for (int k = 0; k < IC; ++k) { ca += cp_w[k] * theta_b[k]; cp2 += cp_w[IC + k] * phi_b[k]; }
    cst[0] = ca; cst[1] = cp2;
  }
  __syncthreads();
  if (tid < 16) {   // a,p: one thread per node
    float au = cst[0], pu = cst[1];
    for (int cc = 0; cc < C; ++cc) {
      float xv = xl[cc * 16 + tid];
      au += lu[cc] * xv;
      pu += lv[cc] * xv;
    }
    ws[OFF_A + (b << 12) + n0 + tid] = au;
    ws[OFF_P + (b << 12) + n0 + tid] = pu;
  }
  const int o = tid & 63, g4 = tid >> 6;
  float bb = g_b[o];
  float acc0 = bb, acc1 = bb, acc2 = bb, acc3 = bb;
  for (int cc = 0; cc < C; ++cc) {
    float gv = gwT[cc * C + o];                 // stride-1: conflict-free
    const float* xr = &xl[cc * 16 + (g4 << 2)]; // wave broadcast
    acc0 += gv * xr[0]; acc1 += gv * xr[1]; acc2 += gv * xr[2]; acc3 += gv * xr[3];
  }
  float* gx = ws + OFF_GX + (size_t)((b << 12) + n0 + (g4 << 2)) * C + o;
  gx[0] = acc0; gx[64] = acc1; gx[128] = acc2; gx[192] = acc3;
  bool nz = CK_NZ(ck0) | CK_NZ(ck1) | CK_NZ(ck2) | CK_NZ(ck3);
  if (__any(nz) && (tid & 63) == 0)
    atomicExch((int*)ws + OFF_FLAG, MAGIC);
}

//========== K2: rank-by-counting + scatter; + C_k scan quarter 1 =============
// grid 512: b = bid>>7, 128 blocks/batch, 32 rows each; 1024 thr = 32r x 32c
__global__ __launch_bounds__(1024) void k2_rank(const float* __restrict__ Ck,
                                                float* __restrict__ ws) {
  __shared__ float lp[N];            // 16 KB: full batch p
  __shared__ int partials[32][33];   // +1 pad
  const int tid = threadIdx.x;
  const int b = blockIdx.x >> 7;
  const int rg = blockIdx.x & 127;
  // ---- C_k scan quarter 1 (loads issued early, consumed at the end) ----
  const float4* c4 = (const float4*)Ck + CKQ;
  float4 ck0, ck1;
  {
    int idx = (blockIdx.x << 10) + tid;   // 524288 threads, 2 f4 each
    ck0 = c4[idx]; ck1 = c4[idx + 524288];
  }
  const float* p = ws + OFF_P + b * N;
  ((float4*)lp)[tid] = ((const float4*)p)[tid];
  const int row = tid & 31, chunk = tid >> 5;
  const int i = (rg << 5) + row;     // batch-local row index
  __syncthreads();
  const float my = lp[i];
  const int c0 = chunk << 7;         // 128 cols per chunk
  const float4* lp4 = (const float4*)(lp + c0);
  int r0 = 0, r1 = 0, r2 = 0, r3 = 0;
  for (int j = 0; j < 32; ++j) {
    float4 v = lp4[j];               // 2 addrs/wave: free 2-way broadcast
    int k = c0 + (j << 2);
    r0 += (v.x < my) || (v.x == my && (k + 0) < i);
    r1 += (v.y < my) || (v.y == my && (k + 1) < i);
    r2 += (v.z < my) || (v.z == my && (k + 2) < i);
    r3 += (v.w < my) || (v.w == my && (k + 3) < i);
  }
  partials[row][chunk] = (r0 + r1) + (r2 + r3);
  __syncthreads();
  if (tid < 32) {                    // one thread per row: finalize + scatter
    int rank = 0;
#pragma unroll
    for (int c = 0; c < 32; ++c) rank += partials[tid][c];
    const int ii = (rg << 5) + tid;
    ws[OFF_Q + (b << 12) + rank] = lp[ii];
    ((int*)ws)[OFF_PERM + (b << 12) + rank] = ii;
  }
  bool nz = CK_NZ(ck0) | CK_NZ(ck1);
  if (__any(nz) && (tid & 63) == 0)
    atomicExch((int*)ws + OFF_FLAG, MAGIC);
}

//========== K34: blocks 0-3 scalar scans; blocks 4.. local prefixes ==========
// Local-prefix blocks (b,c): gather w1/w2 once, write within-chunk
// PreG/SufG AND the chunk totals S1/S2 (old K3-D1 deleted).
// + C_k scan quarters 2+3 (33.5 MB over 266240 threads, 8 f4 bounded).
__global__ __launch_bounds__(1024) void k34_scan_prefix(const float* __restrict__ Ck,
                                                        float* __restrict__ ws) {
  __shared__ float sA[1024], sB[1024];
  const int tid = threadIdx.x;
  const int bid = blockIdx.x;
  const float4* c4 = (const float4*)Ck + 2 * CKQ;
  float4 ck[8];
#pragma unroll
  for (int t = 0; t < 8; ++t) ck[t] = make_float4(0.f, 0.f, 0.f, 0.f);
  {
    int idx = (bid << 10) + tid;         // 266240 threads
#pragma unroll
    for (int t = 0; t < 8; ++t) {
      if (idx < 2 * CKQ) ck[t] = c4[idx];
      idx += 266240;
    }
  }
  if (bid < B) {
    // ---- PreS/SufS shuffle scans (R7-proven, unchanged) ----
    const int b = bid;
    float* wt2 = sA;        // 16
    float* wt1 = sA + 16;   // 16
    float* wo2 = sA + 32;   // 17
    float* wo1 = sA + 49;   // 17
    const float* q = ws + OFF_Q + b * N;
    const float4 qv4 = ((const float4*)q)[tid];
    float e1r[4], e2r[4];
    e2r[0] = expf(0.2f * qv4.x); e1r[0] = expf(qv4.x);
    e2r[1] = expf(0.2f * qv4.y); e1r[1] = expf(qv4.y);
    e2r[2] = expf(0.2f * qv4.z); e1r[2] = expf(qv4.z);
    e2r[3] = expf(0.2f * qv4.w); e1r[3] = expf(qv4.w);
    float s2 = e2r[0] + e2r[1] + e2r[2] + e2r[3];
    float s1 = e1r[0] + e1r[1] + e1r[2] + e1r[3];
    const int lane = tid & 63, wave = tid >> 6;   // 16 waves
    float x2 = s2, x1 = s1;
    for (int off = 1; off < 64; off <<= 1) {
      float t2 = __shfl_up(x2, off, 64);
      float t1 = __shfl_up(x1, off, 64);
      if (lane >= off) { x2 += t2; x1 += t1; }
    }
    if (lane == 63) { wt2[wave] = x2; wt1[wave] = x1; }
    __syncthreads();
    if (wave == 0 && lane < 17) {
      float a2 = 0.f, a1 = 0.f;
      for (int w = 0; w < 16; ++w) {
        if (w < lane) { a2 += wt2[w]; a1 += wt1[w]; }
      }
      wo2[lane] = a2; wo1[lane] = a1;   // wo[16] = grand totals
    }
    __syncthreads();
    const float excl2 = wo2[wave] + (x2 - s2);
    const float incl1 = wo1[wave] + x1;
    const float tot1 = wo1[16];
    float* PreS = ws + OFF_PRES + b * NS;
    float* SufS = ws + OFF_SUFS + b * NS;
    const int base = tid << 2;
    float run = excl2;
#pragma unroll
    for (int j = 0; j < 4; ++j) { PreS[base + j] = run; run += e2r[j]; }
    if (tid == 1023) PreS[N] = run;
    run = tot1 - incl1;
#pragma unroll
    for (int j = 3; j >= 0; --j) { run += e1r[j]; SufS[base + j] = run; }
    if (tid == 1023) SufS[N] = 0.f;
  } else {
    // ---- local prefixes + chunk totals (one block per (b, chunk)) ----
    const int b2 = bid - B;
    const int b = b2 >> 6, c = b2 & 63;
    const int o = tid & 63, kk = tid >> 6;
    const float* q = ws + OFF_Q + b * N;
    const int* perm = (const int*)ws + OFF_PERM + b * N;
    const float* gx = ws + OFF_GX + ((size_t)b << 18);
    float* PreG = ws + OFF_PREG + (size_t)b * NR * 64;
    float* SufG = ws + OFF_SUFG + (size_t)b * NR * 64;
    const int k0 = (c << 6) + (kk << 2);
    float w1[4], w2[4];
    float p1 = 0.f, p2 = 0.f;
#pragma unroll
    for (int r = 0; r < 4; ++r) {
      float qq = q[k0 + r];
      float gg = gx[((size_t)perm[k0 + r] << 6) + o];   // coalesced row gather
      w1[r] = expf(qq) * gg;
      w2[r] = expf(0.2f * qq) * gg;
      p1 += w1[r]; p2 += w2[r];
    }
    sA[(kk << 6) + o] = p2;
    sB[(kk << 6) + o] = p1;
    __syncthreads();
    if (tid < 64) {     // chunk totals -> S1/S2 (absorbs old K3-D1)
      float t2 = 0.f, t1 = 0.f;
#pragma unroll
      for (int g = 0; g < 16; ++g) { t2 += sA[(g << 6) + o]; t1 += sB[(g << 6) + o]; }
      ws[OFF_S2 + (size_t)(((b << 6) + c) << 6) + o] = t2;
      ws[OFF_S1 + (size_t)(((b << 6) + c) << 6) + o] = t1;
    }
    float offp = 0.f, offs = 0.f;     // WITHIN-CHUNK only (offsets moved to K5)
    for (int kp = 0; kp < kk; ++kp) offp += sA[(kp << 6) + o];
    for (int kp = kk + 1; kp < 16; ++kp) offs += sB[(kp << 6) + o];
    float run = offp;                 // exclusive local prefix
#pragma unroll
    for (int r = 0; r < 4; ++r) { PreG[(size_t)(k0 + r) * 64 + o] = run; run += w2[r]; }
    run = offs;                       // inclusive local suffix
#pragma unroll
    for (int r = 3; r >= 0; --r) { run += w1[r]; SufG[(size_t)(k0 + r) * 64 + o] = run; }
  }
  bool nz = (CK_NZ(ck[0]) | CK_NZ(ck[1])) | (CK_NZ(ck[2]) | CK_NZ(ck[3])) |
            (CK_NZ(ck[4]) | CK_NZ(ck[5])) | (CK_NZ(ck[6]) | CK_NZ(ck[7]));
  if (__any(nz) && (tid & 63) == 0)
    atomicExch((int*)ws + OFF_FLAG, MAGIC);
}

//========== K5: chunk scans + per-row threshold lookup + output ==============
// Stages S1/S2 (32KB, L2-hot), two-level parallel chunk scan in LDS, then
// global prefix = cum2[chunk] + PreG_local[k] (resp. suffix). Gated C_k path.
__global__ __launch_bounds__(1024) void k5_out(const float* __restrict__ Ck,
                                               float* __restrict__ ws,
                                               float* __restrict__ y) {
  __shared__ float lq[N];            // 16 KB
  __shared__ float cum2[65 * 64];    // staged S2 then exclusive chunk-prefix
  __shared__ float suf1[65 * 64];    // staged S1 then chunk-suffix (>c)
  __shared__ float part1[1024], part2[1024];
  const int tid = threadIdx.x;
  const int b = blockIdx.x >> 6, rg = blockIdx.x & 63;   // 64 rows per block
  ((float4*)lq)[tid]   = ((const float4*)(ws + OFF_Q + (b << 12)))[tid];
  ((float4*)cum2)[tid] = ((const float4*)(ws + OFF_S2 + ((size_t)b << 12)))[tid];
  ((float4*)suf1)[tid] = ((const float4*)(ws + OFF_S1 + ((size_t)b << 12)))[tid];
  if (tid < 64) suf1[(64 << 6) + tid] = 0.f;   // k==N: no chunks above
  __syncthreads();
  const int o = tid & 63, g = tid >> 6;        // g is wave-uniform
  const int cg0 = g << 2;                      // this wave's 4 chunks
  const float q0 = cum2[(cg0 << 6) + o],       q1 = cum2[((cg0 + 1) << 6) + o],
              q2 = cum2[((cg0 + 2) << 6) + o], q3 = cum2[((cg0 + 3) << 6) + o];
  const float s0 = suf1[(cg0 << 6) + o],       s1v = suf1[((cg0 + 1) << 6) + o],
              s2v = suf1[((cg0 + 2) << 6) + o], s3 = suf1[((cg0 + 3) << 6) + o];
  part2[(g << 6) + o] = (q0 + q1) + (q2 + q3);
  part1[(g << 6) + o] = (s0 + s1v) + (s2v + s3);
  __syncthreads();
  {
    float base2 = 0.f, base1 = 0.f;
    for (int gg = 0; gg < g; ++gg) base2 += part2[(gg << 6) + o];
    for (int gg = g + 1; gg < 16; ++gg) base1 += part1[(gg << 6) + o];
    float run = base2;                          // exclusive prefix of S2
    cum2[(cg0 << 6) + o] = run; run += q0;
    cum2[((cg0 + 1) << 6) + o] = run; run += q1;
    cum2[((cg0 + 2) << 6) + o] = run; run += q2;
    cum2[((cg0 + 3) << 6) + o] = run; run += q3;
    if (g == 15) cum2[(64 << 6) + o] = run;     // grand total (k==N)
    run = base1;                                // strict suffix of S1
    suf1[((cg0 + 3) << 6) + o] = run; run += s3;
    suf1[((cg0 + 2) << 6) + o] = run; run += s2v;
    suf1[((cg0 + 1) << 6) + o] = run; run += s1v;
    suf1[(cg0 << 6) + o] = run;
  }
  // ---- per-row threshold lookup (lq only; overlaps with scan epilogue) ----
  const int io = tid & 63, og = tid >> 6;   // 16 threads/row, 4 o's each
  const int i = (rg << 6) + io;
  float ai = ws[OFF_A + (b << 12) + i];
  float thr = -ai;
  int lo = 0, hi = N;
  while (lo < hi) { int m = (lo + hi) >> 1; if (lq[m] <= thr) lo = m + 1; else hi = m; }
  const int k = lo;  // first index with q > -a_i
  const int kc = k >> 6;                    // chunk of k (64 if k==N)
  float e1 = expf(ai), e2 = expf(0.2f * ai);
  float den = e1 * ws[OFF_SUFS + b * NS + k] + e2 * ws[OFF_PRES + b * NS + k];
  float inv = 1.0f / den;
  float4 pl = {0.f, 0.f, 0.f, 0.f}, sl = pl;
  if (k < N) {
    pl = ((const float4*)(ws + OFF_PREG + ((size_t)b * NR + k) * 64))[og];
    sl = ((const float4*)(ws + OFF_SUFG + ((size_t)b * NR + k) * 64))[og];
  }
  __syncthreads();                          // cum2/suf1 final
  float4 c2  = ((const float4*)(cum2 + (kc << 6)))[og];
  float4 s1g = ((const float4*)(suf1 + (kc << 6)))[og];
  float* yb = y + ((size_t)((b << 6) + (og << 2))) * N + i;
  yb[0]             = (e1 * (s1g.x + sl.x) + e2 * (c2.x + pl.x)) * inv;
  yb[(size_t)N]     = (e1 * (s1g.y + sl.y) + e2 * (c2.y + pl.y)) * inv;
  yb[(size_t)2 * N] = (e1 * (s1g.z + sl.z) + e2 * (c2.z + pl.z)) * inv;
  yb[(size_t)3 * N] = (e1 * (s1g.w + sl.w) + e2 * (c2.w + pl.w)) * inv;
  // ---- gated fallback y += C_k @ g_x (never taken in this harness) ----
  if (((const volatile int*)ws)[OFF_FLAG] == MAGIC) {
    __syncthreads();
    const int it = rg;                        // 64 rows per block
    const int oo = tid & 63, jj = tid >> 6;   // 16 j-stripes
    const float* gx = ws + OFF_GX + ((size_t)b << 18);
    float (*red)[64] = (float(*)[64])lq;      // reuse LDS
    for (int ii = 0; ii < 64; ++ii) {
      int irow = (it << 6) + ii;
      float acc = 0.f;
      for (int j = jj; j < N; j += 16)
        acc += Ck[(size_t)irow * N + j] * gx[((size_t)j << 6) + oo];
      red[jj][oo] = acc;
      __syncthreads();
      if (jj == 0) {
        float s = 0.f;
#pragma unroll
        for (int g2 = 0; g2 < 16; ++g2) s += red[g2][oo];
        y[((size_t)((b << 6) + oo)) * N + irow] += s;
      }
      __syncthreads();
    }
  }
}

extern "C" void kernel_launch(void* const* d_in, const int* in_sizes, int n_in,
                              void* d_out, int out_size, void* d_ws, size_t ws_size,
                              hipStream_t stream) {
  (void)in_sizes; (void)n_in; (void)out_size; (void)ws_size;
  const float* x       = (const float*)d_in[0];
  const float* g_w     = (const float*)d_in[1];
  const float* g_b     = (const float*)d_in[2];
  const float* theta_w = (const float*)d_in[3];
  const float* theta_b = (const float*)d_in[4];
  const float* phi_w   = (const float*)d_in[5];
  const float* phi_b   = (const float*)d_in[6];
  const float* cp_w    = (const float*)d_in[7];
  const float* Ck      = (const float*)d_in[8];
  float* ws = (float*)d_ws;
  float* y  = (float*)d_out;

  hipLaunchKernelGGL(k1_gx, dim3(1024), dim3(256), 0, stream,
                     x, g_w, g_b, theta_w, theta_b, phi_w, phi_b, cp_w, Ck, ws);
  hipLaunchKernelGGL(k2_rank, dim3(512), dim3(1024), 0, stream, Ck, ws);
  hipLaunchKernelGGL(k34_scan_prefix, dim3(B + B * 64), dim3(1024), 0, stream, Ck, ws);
  hipLaunchKernelGGL(k5_out, dim3(B * 64), dim3(1024), 0, stream, Ck, ws, y);
}

// Round 4
// 145.199 us; speedup vs baseline: 1.1142x; 1.0151x over previous
//
#include <hip/hip_runtime.h>

// GlobalGraphConv: B=4, C=64, N=4096, IC=32
// f[i,j] = a_i + p_j (outer sum); lrelu piecewise-linear =>
// exp(lrelu(a_i+p_j)) factorizes per branch; sort p, softmax row = threshold
// lookup into prefix/suffix sums of weighted g_x rows. O(N^2 C) -> O(N C).
// R12: LDS-conflict audit. K1's gwT staging wrote [cc][o] with o constant
// per wave-instr and cc spanning 0..63 -> bank = o&31 for all 64 lanes =
// 64-way write conflict x16 instrs (~2100 cy LDS-pipe per wave, serialized
// CU-wide). Fix: pad gwT stride to 65 -> bank (cc+o)&31, fully spread.
// Hot loop unchanged (still base+imm ds_read, conflict-free). Everything
// else identical to R11's 4-dispatch structure (147.4 us).

#define B  4
#define C  64
#define N  4096
#define IC 32
#define NS 4104   // per-batch stride for PreS/SufS (>= N+1)
#define NR 4097   // rows per batch for PreG/SufG (k = 0..N; row N unused now)
#define MAGIC 0x13572468
#define CKQ 1048576   // C_k quarter size in float4 (N*N/4/4)
#define GWP 65        // padded gwT row stride (kills 64-way bank conflict)

// workspace offsets (in floats)
#define OFF_FLAG   248          // int: C_k nonzero marker (MAGIC if nonzero)
#define OFF_A      256
#define OFF_P      (OFF_A + B*N)
#define OFF_Q      (OFF_P + B*N)
#define OFF_PERM   (OFF_Q + B*N)            // ints
#define OFF_PRES   (OFF_PERM + B*N)
#define OFF_SUFS   (OFF_PRES + B*NS)
#define OFF_S1     (OFF_SUFS + B*NS)        // chunk sums (e^q-weighted) B*64*64
#define OFF_S2     (OFF_S1 + B*64*64)       // chunk sums (e^{0.2q}) B*64*64
#define OFF_GX     (OFF_S2 + B*64*64)       // B*N*64, layout [b][n][o]
#define OFF_PREG   (OFF_GX + B*N*64)        // B*NR*64, layout [b][k][o] (LOCAL)
#define OFF_SUFG   (OFF_PREG + B*NR*64)     // (LOCAL within-chunk)

#define CK_NZ(v) ((v.x != 0.f) | (v.y != 0.f) | (v.z != 0.f) | (v.w != 0.f))

//========== K1: gx = g_w@x + g_b; a,p; + C_k scan quarter 0 ==================
__global__ __launch_bounds__(256) void k1_gx(
    const float* __restrict__ x, const float* __restrict__ g_w,
    const float* __restrict__ g_b, const float* __restrict__ theta_w,
    const float* __restrict__ theta_b, const float* __restrict__ phi_w,
    const float* __restrict__ phi_b, const float* __restrict__ cp_w,
    const float* __restrict__ Ck, float* __restrict__ ws) {
  __shared__ float gwT[GWP * C]; // [cc][o], stride 65: conflict-free T-write
  __shared__ float xl[C * 16];   // [cc][nn]
  __shared__ float lu[C], lv[C], cst[2];
  const int tid = threadIdx.x;
  const int b = blockIdx.x >> 8;           // 256 blocks per batch
  const int n0 = (blockIdx.x & 255) << 4;  // 16 nodes per block
  // ---- C_k scan quarter 0: issue loads first, they fly under the LDS work
  const float4* c4 = (const float4*)Ck;
  float4 ck0, ck1, ck2, ck3;
  {
    int idx = (blockIdx.x << 8) + tid;     // 262144 threads, 4 f4 each
    ck0 = c4[idx]; ck1 = c4[idx + 262144];
    ck2 = c4[idx + 524288]; ck3 = c4[idx + 786432];
  }
  for (int idx = tid; idx < C * C; idx += 256) {
    int o = idx >> 6, cc = idx & 63;
    gwT[cc * GWP + o] = g_w[idx];   // bank (cc+o)&31: spread, conflict-free
  }
  for (int idx = tid; idx < C * 16; idx += 256) {
    int cc = idx >> 4, nn = idx & 15;
    xl[idx] = x[(size_t)((b << 6) + cc) * N + n0 + nn];
  }
  if (tid < 64) {
    float u = 0.f;
    for (int k = 0; k < IC; ++k) u += cp_w[k] * theta_w[k * C + tid];
    lu[tid] = u;
  } else if (tid < 128) {
    int c = tid - 64;
    float v = 0.f;
    for (int k = 0; k < IC; ++k) v += cp_w[IC + k] * phi_w[k * C + c];
    lv[c] = v;
  } else if (tid == 128) {
    float ca = 0.f, cp2 = 0.f;
    for (int k = 0; k < IC; ++k) { ca += cp_w[k] * theta_b[k]; cp2 += cp_w[IC + k] * phi_b[k]; }
    cst[0] = ca; cst[1] = cp2;
  }
  __syncthreads();
  if (tid < 16) {   // a,p: one thread per node
    float au = cst[0], pu = cst[1];
    for (int cc = 0; cc < C; ++cc) {
      float xv = xl[cc * 16 + tid];
      au += lu[cc] * xv;
      pu += lv[cc] * xv;
    }
    ws[OFF_A + (b << 12) + n0 + tid] = au;
    ws[OFF_P + (b << 12) + n0 + tid] = pu;
  }
  const int o = tid & 63, g4 = tid >> 6;
  float bb = g_b[o];
  float acc0 = bb, acc1 = bb, acc2 = bb, acc3 = bb;
  for (int cc = 0; cc < C; ++cc) {
    float gv = gwT[cc * GWP + o];               // stride-1 lanes: conflict-free
    const float* xr = &xl[cc * 16 + (g4 << 2)]; // wave broadcast
    acc0 += gv * xr[0]; acc1 += gv * xr[1]; acc2 += gv * xr[2]; acc3 += gv * xr[3];
  }
  float* gx = ws + OFF_GX + (size_t)((b << 12) + n0 + (g4 << 2)) * C + o;
  gx[0] = acc0; gx[64] = acc1; gx[128] = acc2; gx[192] = acc3;
  bool nz = CK_NZ(ck0) | CK_NZ(ck1) | CK_NZ(ck2) | CK_NZ(ck3);
  if (__any(nz) && (tid & 63) == 0)
    atomicExch((int*)ws + OFF_FLAG, MAGIC);
}

//========== K2: rank-by-counting + scatter; + C_k scan quarter 1 =============
// grid 512: b = bid>>7, 128 blocks/batch, 32 rows each; 1024 thr = 32r x 32c
__global__ __launch_bounds__(1024) void k2_rank(const float* __restrict__ Ck,
                                                float* __restrict__ ws) {
  __shared__ float lp[N];            // 16 KB: full batch p
  __shared__ int partials[32][33];   // +1 pad
  const int tid = threadIdx.x;
  const int b = blockIdx.x >> 7;
  const int rg = blockIdx.x & 127;
  // ---- C_k scan quarter 1 (loads issued early, consumed at the end) ----
  const float4* c4 = (const float4*)Ck + CKQ;
  float4 ck0, ck1;
  {
    int idx = (blockIdx.x << 10) + tid;   // 524288 threads, 2 f4 each
    ck0 = c4[idx]; ck1 = c4[idx + 524288];
  }
  const float* p = ws + OFF_P + b * N;
  ((float4*)lp)[tid] = ((const float4*)p)[tid];
  const int row = tid & 31, chunk = tid >> 5;
  const int i = (rg << 5) + row;     // batch-local row index
  __syncthreads();
  const float my = lp[i];
  const int c0 = chunk << 7;         // 128 cols per chunk
  const float4* lp4 = (const float4*)(lp + c0);
  int r0 = 0, r1 = 0, r2 = 0, r3 = 0;
  for (int j = 0; j < 32; ++j) {
    float4 v = lp4[j];               // 2 addrs/wave: free 2-way broadcast
    int k = c0 + (j << 2);
    r0 += (v.x < my) || (v.x == my && (k + 0) < i);
    r1 += (v.y < my) || (v.y == my && (k + 1) < i);
    r2 += (v.z < my) || (v.z == my && (k + 2) < i);
    r3 += (v.w < my) || (v.w == my && (k + 3) < i);
  }
  partials[row][chunk] = (r0 + r1) + (r2 + r3);
  __syncthreads();
  if (tid < 32) {                    // one thread per row: finalize + scatter
    int rank = 0;
#pragma unroll
    for (int c = 0; c < 32; ++c) rank += partials[tid][c];
    const int ii = (rg << 5) + tid;
    ws[OFF_Q + (b << 12) + rank] = lp[ii];
    ((int*)ws)[OFF_PERM + (b << 12) + rank] = ii;
  }
  bool nz = CK_NZ(ck0) | CK_NZ(ck1);
  if (__any(nz) && (tid & 63) == 0)
    atomicExch((int*)ws + OFF_FLAG, MAGIC);
}

//========== K34: blocks 0-3 scalar scans; blocks 4.. local prefixes ==========
// Local-prefix blocks (b,c): gather w1/w2 once, write within-chunk
// PreG/SufG AND the chunk totals S1/S2 (old K3-D1 deleted).
// + C_k scan quarters 2+3 (33.5 MB over 266240 threads, 8 f4 bounded).
__global__ __launch_bounds__(1024) void k34_scan_prefix(const float* __restrict__ Ck,
                                                        float* __restrict__ ws) {
  __shared__ float sA[1024], sB[1024];
  const int tid = threadIdx.x;
  const int bid = blockIdx.x;
  const float4* c4 = (const float4*)Ck + 2 * CKQ;
  float4 ck[8];
#pragma unroll
  for (int t = 0; t < 8; ++t) ck[t] = make_float4(0.f, 0.f, 0.f, 0.f);
  {
    int idx = (bid << 10) + tid;         // 266240 threads
#pragma unroll
    for (int t = 0; t < 8; ++t) {
      if (idx < 2 * CKQ) ck[t] = c4[idx];
      idx += 266240;
    }
  }
  if (bid < B) {
    // ---- PreS/SufS shuffle scans (R7-proven, unchanged) ----
    const int b = bid;
    float* wt2 = sA;        // 16
    float* wt1 = sA + 16;   // 16
    float* wo2 = sA + 32;   // 17
    float* wo1 = sA + 49;   // 17
    const float* q = ws + OFF_Q + b * N;
    const float4 qv4 = ((const float4*)q)[tid];
    float e1r[4], e2r[4];
    e2r[0] = expf(0.2f * qv4.x); e1r[0] = expf(qv4.x);
    e2r[1] = expf(0.2f * qv4.y); e1r[1] = expf(qv4.y);
    e2r[2] = expf(0.2f * qv4.z); e1r[2] = expf(qv4.z);
    e2r[3] = expf(0.2f * qv4.w); e1r[3] = expf(qv4.w);
    float s2 = e2r[0] + e2r[1] + e2r[2] + e2r[3];
    float s1 = e1r[0] + e1r[1] + e1r[2] + e1r[3];
    const int lane = tid & 63, wave = tid >> 6;   // 16 waves
    float x2 = s2, x1 = s1;
    for (int off = 1; off < 64; off <<= 1) {
      float t2 = __shfl_up(x2, off, 64);
      float t1 = __shfl_up(x1, off, 64);
      if (lane >= off) { x2 += t2; x1 += t1; }
    }
    if (lane == 63) { wt2[wave] = x2; wt1[wave] = x1; }
    __syncthreads();
    if (wave == 0 && lane < 17) {
      float a2 = 0.f, a1 = 0.f;
      for (int w = 0; w < 16; ++w) {
        if (w < lane) { a2 += wt2[w]; a1 += wt1[w]; }
      }
      wo2[lane] = a2; wo1[lane] = a1;   // wo[16] = grand totals
    }
    __syncthreads();
    const float excl2 = wo2[wave] + (x2 - s2);
    const float incl1 = wo1[wave] + x1;
    const float tot1 = wo1[16];
    float* PreS = ws + OFF_PRES + b * NS;
    float* SufS = ws + OFF_SUFS + b * NS;
    const int base = tid << 2;
    float run = excl2;
#pragma unroll
    for (int j = 0; j < 4; ++j) { PreS[base + j] = run; run += e2r[j]; }
    if (tid == 1023) PreS[N] = run;
    run = tot1 - incl1;
#pragma unroll
    for (int j = 3; j >= 0; --j) { run += e1r[j]; SufS[base + j] = run; }
    if (tid == 1023) SufS[N] = 0.f;
  } else {
    // ---- local prefixes + chunk totals (one block per (b, chunk)) ----
    const int b2 = bid - B;
    const int b = b2 >> 6, c = b2 & 63;
    const int o = tid & 63, kk = tid >> 6;
    const float* q = ws + OFF_Q + b * N;
    const int* perm = (const int*)ws + OFF_PERM + b * N;
    const float* gx = ws + OFF_GX + ((size_t)b << 18);
    float* PreG = ws + OFF_PREG + (size_t)b * NR * 64;
    float* SufG = ws + OFF_SUFG + (size_t)b * NR * 64;
    const int k0 = (c << 6) + (kk << 2);
    float w1[4], w2[4];
    float p1 = 0.f, p2 = 0.f;
#pragma unroll
    for (int r = 0; r < 4; ++r) {
      float qq = q[k0 + r];
      float gg = gx[((size_t)perm[k0 + r] << 6) + o];   // coalesced row gather
      w1[r] = expf(qq) * gg;
      w2[r] = expf(0.2f * qq) * gg;
      p1 += w1[r]; p2 += w2[r];
    }
    sA[(kk << 6) + o] = p2;
    sB[(kk << 6) + o] = p1;
    __syncthreads();
    if (tid < 64) {     // chunk totals -> S1/S2 (absorbs old K3-D1)
      float t2 = 0.f, t1 = 0.f;
#pragma unroll
      for (int g = 0; g < 16; ++g) { t2 += sA[(g << 6) + o]; t1 += sB[(g << 6) + o]; }
      ws[OFF_S2 + (size_t)(((b << 6) + c) << 6) + o] = t2;
      ws[OFF_S1 + (size_t)(((b << 6) + c) << 6) + o] = t1;
    }
    float offp = 0.f, offs = 0.f;     // WITHIN-CHUNK only (offsets moved to K5)
    for (int kp = 0; kp < kk; ++kp) offp += sA[(kp << 6) + o];
    for (int kp = kk + 1; kp < 16; ++kp) offs += sB[(kp << 6) + o];
    float run = offp;                 // exclusive local prefix
#pragma unroll
    for (int r = 0; r < 4; ++r) { PreG[(size_t)(k0 + r) * 64 + o] = run; run += w2[r]; }
    run = offs;                       // inclusive local suffix
#pragma unroll
    for (int r = 3; r >= 0; --r) { run += w1[r]; SufG[(size_t)(k0 + r) * 64 + o] = run; }
  }
  bool nz = (CK_NZ(ck[0]) | CK_NZ(ck[1])) | (CK_NZ(ck[2]) | CK_NZ(ck[3])) |
            (CK_NZ(ck[4]) | CK_NZ(ck[5])) | (CK_NZ(ck[6]) | CK_NZ(ck[7]));
  if (__any(nz) && (tid & 63) == 0)
    atomicExch((int*)ws + OFF_FLAG, MAGIC);
}

//========== K5: chunk scans + per-row threshold lookup + output ==============
// Stages S1/S2 (32KB, L2-hot), two-level parallel chunk scan in LDS, then
// global prefix = cum2[chunk] + PreG_local[k] (resp. suffix). Gated C_k path.
__global__ __launch_bounds__(1024) void k5_out(const float* __restrict__ Ck,
                                               float* __restrict__ ws,
                                               float* __restrict__ y) {
  __shared__ float lq[N];            // 16 KB
  __shared__ float cum2[65 * 64];    // staged S2 then exclusive chunk-prefix
  __shared__ float suf1[65 * 64];    // staged S1 then chunk-suffix (>c)
  __shared__ float part1[1024], part2[1024];
  const int tid = threadIdx.x;
  const int b = blockIdx.x >> 6, rg = blockIdx.x & 63;   // 64 rows per block
  ((float4*)lq)[tid]   = ((const float4*)(ws + OFF_Q + (b << 12)))[tid];
  ((float4*)cum2)[tid] = ((const float4*)(ws + OFF_S2 + ((size_t)b << 12)))[tid];
  ((float4*)suf1)[tid] = ((const float4*)(ws + OFF_S1 + ((size_t)b << 12)))[tid];
  if (tid < 64) suf1[(64 << 6) + tid] = 0.f;   // k==N: no chunks above
  __syncthreads();
  const int o = tid & 63, g = tid >> 6;        // g is wave-uniform
  const int cg0 = g << 2;                      // this wave's 4 chunks
  const float q0 = cum2[(cg0 << 6) + o],       q1 = cum2[((cg0 + 1) << 6) + o],
              q2 = cum2[((cg0 + 2) << 6) + o], q3 = cum2[((cg0 + 3) << 6) + o];
  const float s0 = suf1[(cg0 << 6) + o],       s1v = suf1[((cg0 + 1) << 6) + o],
              s2v = suf1[((cg0 + 2) << 6) + o], s3 = suf1[((cg0 + 3) << 6) + o];
  part2[(g << 6) + o] = (q0 + q1) + (q2 + q3);
  part1[(g << 6) + o] = (s0 + s1v) + (s2v + s3);
  __syncthreads();
  {
    float base2 = 0.f, base1 = 0.f;
    for (int gg = 0; gg < g; ++gg) base2 += part2[(gg << 6) + o];
    for (int gg = g + 1; gg < 16; ++gg) base1 += part1[(gg << 6) + o];
    float run = base2;                          // exclusive prefix of S2
    cum2[(cg0 << 6) + o] = run; run += q0;
    cum2[((cg0 + 1) << 6) + o] = run; run += q1;
    cum2[((cg0 + 2) << 6) + o] = run; run += q2;
    cum2[((cg0 + 3) << 6) + o] = run; run += q3;
    if (g == 15) cum2[(64 << 6) + o] = run;     // grand total (k==N)
    run = base1;                                // strict suffix of S1
    suf1[((cg0 + 3) << 6) + o] = run; run += s3;
    suf1[((cg0 + 2) << 6) + o] = run; run += s2v;
    suf1[((cg0 + 1) << 6) + o] = run; run += s1v;
    suf1[(cg0 << 6) + o] = run;
  }
  // ---- per-row threshold lookup (lq only; overlaps with scan epilogue) ----
  const int io = tid & 63, og = tid >> 6;   // 16 threads/row, 4 o's each
  const int i = (rg << 6) + io;
  float ai = ws[OFF_A + (b << 12) + i];
  float thr = -ai;
  int lo = 0, hi = N;
  while (lo < hi) { int m = (lo + hi) >> 1; if (lq[m] <= thr) lo = m + 1; else hi = m; }
  const int k = lo;  // first index with q > -a_i
  const int kc = k >> 6;                    // chunk of k (64 if k==N)
  float e1 = expf(ai), e2 = expf(0.2f * ai);
  float den = e1 * ws[OFF_SUFS + b * NS + k] + e2 * ws[OFF_PRES + b * NS + k];
  float inv = 1.0f / den;
  float4 pl = {0.f, 0.f, 0.f, 0.f}, sl = pl;
  if (k < N) {
    pl = ((const float4*)(ws + OFF_PREG + ((size_t)b * NR + k) * 64))[og];
    sl = ((const float4*)(ws + OFF_SUFG + ((size_t)b * NR + k) * 64))[og];
  }
  __syncthreads();                          // cum2/suf1 final
  float4 c2  = ((const float4*)(cum2 + (kc << 6)))[og];
  float4 s1g = ((const float4*)(suf1 + (kc << 6)))[og];
  float* yb = y + ((size_t)((b << 6) + (og << 2))) * N + i;
  yb[0]             = (e1 * (s1g.x + sl.x) + e2 * (c2.x + pl.x)) * inv;
  yb[(size_t)N]     = (e1 * (s1g.y + sl.y) + e2 * (c2.y + pl.y)) * inv;
  yb[(size_t)2 * N] = (e1 * (s1g.z + sl.z) + e2 * (c2.z + pl.z)) * inv;
  yb[(size_t)3 * N] = (e1 * (s1g.w + sl.w) + e2 * (c2.w + pl.w)) * inv;
  // ---- gated fallback y += C_k @ g_x (never taken in this harness) ----
  if (((const volatile int*)ws)[OFF_FLAG] == MAGIC) {
    __syncthreads();
    const int it = rg;                        // 64 rows per block
    const int oo = tid & 63, jj = tid >> 6;   // 16 j-stripes
    const float* gx = ws + OFF_GX + ((size_t)b << 18);
    float (*red)[64] = (float(*)[64])lq;      // reuse LDS
    for (int ii = 0; ii < 64; ++ii) {
      int irow = (it << 6) + ii;
      float acc = 0.f;
      for (int j = jj; j < N; j += 16)
        acc += Ck[(size_t)irow * N + j] * gx[((size_t)j << 6) + oo];
      red[jj][oo] = acc;
      __syncthreads();
      if (jj == 0) {
        float s = 0.f;
#pragma unroll
        for (int g2 = 0; g2 < 16; ++g2) s += red[g2][oo];
        y[((size_t)((b << 6) + oo)) * N + irow] += s;
      }
      __syncthreads();
    }
  }
}

extern "C" void kernel_launch(void* const* d_in, const int* in_sizes, int n_in,
                              void* d_out, int out_size, void* d_ws, size_t ws_size,
                              hipStream_t stream) {
  (void)in_sizes; (void)n_in; (void)out_size; (void)ws_size;
  const float* x       = (const float*)d_in[0];
  const float* g_w     = (const float*)d_in[1];
  const float* g_b     = (const float*)d_in[2];
  const float* theta_w = (const float*)d_in[3];
  const float* theta_b = (const float*)d_in[4];
  const float* phi_w   = (const float*)d_in[5];
  const float* phi_b   = (const float*)d_in[6];
  const float* cp_w    = (const float*)d_in[7];
  const float* Ck      = (const float*)d_in[8];
  float* ws = (float*)d_ws;
  float* y  = (float*)d_out;

  hipLaunchKernelGGL(k1_gx, dim3(1024), dim3(256), 0, stream,
                     x, g_w, g_b, theta_w, theta_b, phi_w, phi_b, cp_w, Ck, ws);
  hipLaunchKernelGGL(k2_rank, dim3(512), dim3(1024), 0, stream, Ck, ws);
  hipLaunchKernelGGL(k34_scan_prefix, dim3(B + B * 64), dim3(1024), 0, stream, Ck, ws);
  hipLaunchKernelGGL(k5_out, dim3(B * 64), dim3(1024), 0, stream, Ck, ws, y);
}